// Round 13
// baseline (103.738 us; speedup 1.0000x reference)
//
#include <hip/hip_runtime.h>
#include <hip/hip_bf16.h>
#include <math.h>

#define T_DIM 2048
#define B_DIM 16
#define M_DIM 512
#define H_DIM 256
#define KC 512
#define K_DIM 512
#define CHUNK 64
#define NCHUNK 32
#define NTILE 16            // K / 32 (pre-tiled granule count per 128-panel)

typedef unsigned short ushort_t;
typedef __attribute__((ext_vector_type(8))) short short8;
typedef __attribute__((ext_vector_type(8))) unsigned short ushort8;
typedef __attribute__((ext_vector_type(4))) float f32x4;

// ---- workspace layout (float offsets) ----
#define WS_CARRY 0            // 262144 floats (32*16*512)
#define WS_WB_BF 262144       // 262144 ushorts tiled
#define WS_WC_BF 393216       // 262144 ushorts tiled
#define WS_BU    8912896      // 16777216 ushorts: Bu TILED, then H in place

// tiled index (ushorts): element (n,k) -> ((n/128)*16 + k/32)*4096 +
//   ((k/8)%4)*1024 + (n%128)*8 + k%8   — linear LDS staging order.
__device__ inline int tidx(int n, int k) {
    return (((n >> 7) * 16 + (k >> 5)) << 12) + (((k >> 3) & 3) << 10)
         + ((n & 127) << 3) + (k & 7);
}

__device__ inline ushort_t f2bf(float f) {
    __hip_bfloat16 h = __float2bfloat16(f);
    return *reinterpret_cast<ushort_t*>(&h);
}
__device__ inline float bf2f(ushort_t u) {
    union { unsigned int i; float f; } v;
    v.i = ((unsigned int)u) << 16;
    return v.f;
}

// bf16 weights pre-tiled (linear output idx, gather reads; 1MB, trivial).
__global__ void prep_w(const float* __restrict__ B_re, const float* __restrict__ B_im,
                       const float* __restrict__ gamma_log,
                       const float* __restrict__ C_re, const float* __restrict__ C_im,
                       ushort_t* __restrict__ wb, ushort_t* __restrict__ wc) {
    int idx = blockIdx.x * blockDim.x + threadIdx.x;  // 0..262143
    int e    = idx & 7;
    int slot = (idx >> 3) & 511;
    int row  = slot & 127;
    int ks   = slot >> 7;
    int t    = (idx >> 12) & 15;
    int blk  = idx >> 16;
    int j = blk * 128 + row;
    int k = t * 32 + ks * 8 + e;
    float v;
    if (j < 256) v = expf(gamma_log[j])       * B_re[j * 512 + k];
    else         v = expf(gamma_log[j - 256]) * B_im[(j - 256) * 512 + k];
    wb[idx] = f2bf(v);
    float w;
    if (k < 256) w =  C_re[j * 256 + k];
    else         w = -C_im[j * 256 + (k - 256)];
    wc[idx] = f2bf(w);
}

// NT GEMM via MFMA bf16, 256x256 tile, BK=64, 8 waves (512 thr). R12-proven
// 2-phase loop (2 LDS dbufs, unroll-2 static indices, plain __syncthreads).
// MODE 0 (GEMM1): A = X fp32 natural, REG-STAGED (8x float4 -> cvt ->
//   4x ds_write_b128; thread = (row=tid>>1, khalf=(tid&1)*32) -> 128B
//   contiguous global, 2-way (free) LDS write). Swapped-operand MFMA,
//   packed uint2 stores into TILED Bu. W via global_load_lds.
// MODE 1 (GEMM2): A bf16 tiled via global_load_lds; fp32 natural out
//   + D[col]*X(fp32) epilogue.
// Grid 1-D 256: id = g*16 + j*8 + x -> rb = g*8+x (0..127), nb = j (0..1);
// the 2 col-panels of a row-panel are spaced 8 ids -> same XCD.
template <int MODE>
__global__ __launch_bounds__(512) void gemm_mfma(
    const void* __restrict__ Aptr, const ushort_t* __restrict__ W,
    void* __restrict__ Cv, const float* __restrict__ Dv,
    const float* __restrict__ X) {
    __shared__ ushort_t Asl[2][4][4096];   // [buf][q*2+kk][slot] : 64KB
    __shared__ ushort_t Bsl[2][4][4096];   // 64KB
    const int tid = threadIdx.x;           // 0..511
    const int id = blockIdx.x;
    const int rb = ((id >> 4) << 3) + (id & 7);   // row-panel-pair 0..127
    const int nb = (id >> 3) & 1;                 // col-panel-pair 0..1
    const int bm = rb << 8, bn = nb << 8;
    const int lane = tid & 63, wid = tid >> 6;    // 8 waves
    const int wr  = (wid >> 2) << 7;       // 0 / 128
    const int wcc = (wid & 3) << 6;        // 0,64,128,192
    const int l16 = lane & 15, ksl = lane >> 4;

    const ushort_t* At = (const ushort_t*)Aptr;  // MODE 1: tiled bf16 H
    const float*    Xf = (const float*)Aptr;     // MODE 0: natural fp32 X

    // MODE 0 reg-staging map: row ar = tid>>1, k-half = (tid&1)*32
    const int ar  = tid >> 1;
    const int akh = (tid & 1) << 5;        // 0 / 32
    const int asub = ((ar >> 7) << 1) + (tid & 1);
    const int arow127 = ar & 127;

    f32x4 acc[MODE == 0 ? 4 : 8][MODE == 0 ? 8 : 4] = {};
    float4 av[8];

    auto stageB = [&](int t, int buf) {
#pragma unroll
        for (int q = 0; q < 2; ++q)
#pragma unroll
            for (int kk = 0; kk < 2; ++kk) {
                size_t bb = ((size_t)((2 * nb + q) * NTILE + (2 * t + kk))) * 4096;
                __builtin_amdgcn_global_load_lds(
                    (const __attribute__((address_space(1))) void*)(W + bb + tid * 8),
                    (__attribute__((address_space(3))) void*)(&Bsl[buf][q * 2 + kk][tid * 8]),
                    16, 0, 0);
            }
    };
    auto stageA = [&](int t, int buf) {   // MODE 1 only
#pragma unroll
        for (int q = 0; q < 2; ++q)
#pragma unroll
            for (int kk = 0; kk < 2; ++kk) {
                size_t ab = ((size_t)((2 * rb + q) * NTILE + (2 * t + kk))) * 4096;
                __builtin_amdgcn_global_load_lds(
                    (const __attribute__((address_space(1))) void*)(At + ab + tid * 8),
                    (__attribute__((address_space(3))) void*)(&Asl[buf][q * 2 + kk][tid * 8]),
                    16, 0, 0);
            }
    };
    auto loadA = [&](int t) {             // MODE 0 only: 128B contiguous
        const float* p = Xf + (size_t)(bm + ar) * 512 + t * 64 + akh;
#pragma unroll
        for (int i = 0; i < 8; ++i) av[i] = *(const float4*)(p + i * 4);
    };
    auto writeA = [&](int buf) {          // MODE 0 only
#pragma unroll
        for (int i = 0; i < 4; ++i) {
            float4 a = av[2 * i], b = av[2 * i + 1];
            ushort8 u;
            u[0] = f2bf(a.x); u[1] = f2bf(a.y); u[2] = f2bf(a.z); u[3] = f2bf(a.w);
            u[4] = f2bf(b.x); u[5] = f2bf(b.y); u[6] = f2bf(b.z); u[7] = f2bf(b.w);
            *(ushort8*)(&Asl[buf][asub][(i * 128 + arow127) * 8]) = u;
        }
    };

    if constexpr (MODE == 0) {
        stageB(0, 0);
        loadA(0);
        writeA(0);
    } else {
        stageA(0, 0);
        stageB(0, 0);
    }
    __syncthreads();

    int cur = 0;
#pragma unroll 2
    for (int t = 0; t < 8; ++t) {
        const int nxt = cur ^ 1;
        if (t + 1 < 8) {
            stageB(t + 1, nxt);
            if constexpr (MODE == 0) loadA(t + 1);
            else                     stageA(t + 1, nxt);
        }
#pragma unroll
        for (int kk = 0; kk < 2; ++kk) {
            short8 afr[8], bfr[4];
#pragma unroll
            for (int m = 0; m < 8; ++m) {
                int row = wr + m * 16 + l16;       // 0..255
                afr[m] = *(const short8*)(&Asl[cur][(row >> 7) * 2 + kk]
                                              [ksl * 1024 + (row & 127) * 8]);
            }
#pragma unroll
            for (int n = 0; n < 4; ++n) {
                int col = wcc + n * 16 + l16;      // 0..255
                bfr[n] = *(const short8*)(&Bsl[cur][(col >> 7) * 2 + kk]
                                              [ksl * 1024 + (col & 127) * 8]);
            }
            if constexpr (MODE == 0) {
#pragma unroll
                for (int i = 0; i < 4; ++i)       // i: W-frag (k axis)
#pragma unroll
                    for (int j = 0; j < 8; ++j)   // j: X-frag (n axis)
                        acc[i][j] = __builtin_amdgcn_mfma_f32_16x16x32_bf16(
                            bfr[i], afr[j], acc[i][j], 0, 0, 0);
            } else {
#pragma unroll
                for (int i = 0; i < 8; ++i)       // i: A-frag (H rows)
#pragma unroll
                    for (int j = 0; j < 4; ++j)   // j: W-frag (out cols)
                        acc[i][j] = __builtin_amdgcn_mfma_f32_16x16x32_bf16(
                            afr[i], bfr[j], acc[i][j], 0, 0, 0);
            }
        }
        if constexpr (MODE == 0) { if (t + 1 < 8) writeA(nxt); }
        __syncthreads();
        cur = nxt;
    }

    const int fr = (lane >> 4) << 2;
    if constexpr (MODE == 0) {
        // D row axis = W-col k (4 consecutive), D col axis (l16) = X-row n.
        ushort_t* Bu = (ushort_t*)Cv;
#pragma unroll
        for (int i = 0; i < 4; ++i) {
            int k0 = bn + wcc + i * 16 + fr;      // 4-aligned k quad
#pragma unroll
            for (int j = 0; j < 8; ++j) {
                int n = bm + wr + j * 16 + l16;
                uint2 p;
                p.x = (unsigned int)f2bf(acc[i][j][0])
                    | ((unsigned int)f2bf(acc[i][j][1]) << 16);
                p.y = (unsigned int)f2bf(acc[i][j][2])
                    | ((unsigned int)f2bf(acc[i][j][3]) << 16);
                size_t off = ((size_t)((n >> 7) * 16 + (k0 >> 5)) << 12)
                           + (((k0 >> 3) & 3) << 10) + ((n & 127) << 3) + (k0 & 7);
                *(uint2*)(&Bu[off]) = p;
            }
        }
    } else {
        // natural fp32 out: row = H-row, col via l16 (64B coalesced)
#pragma unroll
        for (int i = 0; i < 8; ++i) {
#pragma unroll
            for (int j = 0; j < 4; ++j) {
#pragma unroll
                for (int r = 0; r < 4; ++r) {
                    int row = bm + wr + i * 16 + fr + r;
                    int col = bn + wcc + j * 16 + l16;
                    size_t o = (size_t)row * 512 + col;
                    ((float*)Cv)[o] = acc[i][j][r] + Dv[col] * X[o];
                }
            }
        }
    }
}

// Scan pass A: block = (chunk c, h-slab s); threads = 16 b x 16 h-pairs.
// Batch-8 loads (addresses independent of recurrence) to hide HBM latency.
__global__ __launch_bounds__(256) void scan_local(const float* __restrict__ nu_log,
        const float* __restrict__ theta_log, float* __restrict__ ws) {
    const int c = blockIdx.x;
    const int s = blockIdx.y;
    const int b = threadIdx.x >> 4;
    const int h0 = s * 32 + (threadIdx.x & 15) * 2;
    float lr[2], li[2];
#pragma unroll
    for (int q = 0; q < 2; ++q) {
        float nu = expf(nu_log[h0 + q]);
        float th = expf(theta_log[h0 + q]);
        float r  = expf(-nu);
        lr[q] = r * cosf(th); li[q] = r * sinf(th);
    }
    const ushort_t* Bu = (const ushort_t*)(ws + WS_BU);
    float hr[2] = {0.f, 0.f}, hi[2] = {0.f, 0.f};
    for (int l0 = 0; l0 < CHUNK; l0 += 8) {
        unsigned int vre[8], vim[8];
#pragma unroll
        for (int u = 0; u < 8; ++u) {
            int n = (c * CHUNK + l0 + u) * B_DIM + b;
            vre[u] = *(const unsigned int*)(&Bu[tidx(n, h0)]);
            vim[u] = *(const unsigned int*)(&Bu[tidx(n, h0 + 256)]);
        }
#pragma unroll
        for (int u = 0; u < 8; ++u) {
#pragma unroll
            for (int q = 0; q < 2; ++q) {
                float br = bf2f((ushort_t)(q ? (vre[u] >> 16) : (vre[u] & 0xffff)));
                float bi = bf2f((ushort_t)(q ? (vim[u] >> 16) : (vim[u] & 0xffff)));
                float nr = fmaf(lr[q], hr[q], fmaf(-li[q], hi[q], br));
                float ni = fmaf(lr[q], hi[q], fmaf(li[q], hr[q], bi));
                hr[q] = nr; hi[q] = ni;
            }
        }
    }
    size_t cb = (size_t)(c * B_DIM + b) * KC;
    *(float2*)(&ws[WS_CARRY + cb + h0])       = make_float2(hr[0], hr[1]);
    *(float2*)(&ws[WS_CARRY + cb + 256 + h0]) = make_float2(hi[0], hi[1]);
}

// Pass B: sequential over 32 chunk aggregates; h_final planar re/im to out tail.
__global__ __launch_bounds__(256) void scan_carry(const float* __restrict__ nu_log,
        const float* __restrict__ theta_log, float* __restrict__ ws,
        const float* __restrict__ h_re, const float* __restrict__ h_im,
        float* __restrict__ out, int out_size) {
    const int b = blockIdx.x;
    const int h = threadIdx.x;
    const float nu = expf(nu_log[h]);
    const float th = expf(theta_log[h]);
    const float rL  = expf(-64.f * nu);
    const float thL = 64.f * th;
    const float Lr = rL * cosf(thL), Li = rL * sinf(thL);
    float cr = h_re[b * H_DIM + h], ci = h_im[b * H_DIM + h];
    for (int c = 0; c < NCHUNK; ++c) {
        size_t cidx = ((size_t)(c * B_DIM + b)) * KC + h;
        float sr = ws[WS_CARRY + cidx], si = ws[WS_CARRY + cidx + 256];
        ws[WS_CARRY + cidx]       = cr;
        ws[WS_CARRY + cidx + 256] = ci;
        float nr = fmaf(Lr, cr, fmaf(-Li, ci, sr));
        float ni = fmaf(Lr, ci, fmaf(Li, cr, si));
        cr = nr; ci = ni;
    }
    const size_t base = (size_t)T_DIM * B_DIM * M_DIM;
    const size_t idx  = (size_t)b * H_DIM + h;
    size_t ore = base + idx;
    size_t oim = base + (size_t)B_DIM * H_DIM + idx;
    if (ore < (size_t)out_size) out[ore] = cr;
    if (oim < (size_t)out_size) out[oim] = ci;
}

// Pass C: replay chunk from carry-in; overwrite Bu IN PLACE (tiled) with h_t.
__global__ __launch_bounds__(256) void scan_apply(const float* __restrict__ nu_log,
        const float* __restrict__ theta_log, float* __restrict__ ws) {
    const int c = blockIdx.x;
    const int s = blockIdx.y;
    const int b = threadIdx.x >> 4;
    const int h0 = s * 32 + (threadIdx.x & 15) * 2;
    float lr[2], li[2];
#pragma unroll
    for (int q = 0; q < 2; ++q) {
        float nu = expf(nu_log[h0 + q]);
        float th = expf(theta_log[h0 + q]);
        float r  = expf(-nu);
        lr[q] = r * cosf(th); li[q] = r * sinf(th);
    }
    ushort_t* Bu = (ushort_t*)(ws + WS_BU);
    size_t cb = (size_t)(c * B_DIM + b) * KC;
    float2 f2r = *(const float2*)(&ws[WS_CARRY + cb + h0]);
    float2 f2i = *(const float2*)(&ws[WS_CARRY + cb + 256 + h0]);
    float hr[2] = {f2r.x, f2r.y}, hi[2] = {f2i.x, f2i.y};
    for (int l0 = 0; l0 < CHUNK; l0 += 8) {
        unsigned int vre[8], vim[8];
        int ire[8], iim[8];
#pragma unroll
        for (int u = 0; u < 8; ++u) {
            int n = (c * CHUNK + l0 + u) * B_DIM + b;
            ire[u] = tidx(n, h0);
            iim[u] = tidx(n, h0 + 256);
            vre[u] = *(const unsigned int*)(&Bu[ire[u]]);
            vim[u] = *(const unsigned int*)(&Bu[iim[u]]);
        }
#pragma unroll
        for (int u = 0; u < 8; ++u) {
#pragma unroll
            for (int q = 0; q < 2; ++q) {
                float br = bf2f((ushort_t)(q ? (vre[u] >> 16) : (vre[u] & 0xffff)));
                float bi = bf2f((ushort_t)(q ? (vim[u] >> 16) : (vim[u] & 0xffff)));
                float nr = fmaf(lr[q], hr[q], fmaf(-li[q], hi[q], br));
                float ni = fmaf(lr[q], hi[q], fmaf(li[q], hr[q], bi));
                hr[q] = nr; hi[q] = ni;
            }
            *(unsigned int*)(&Bu[ire[u]]) =
                (unsigned int)f2bf(hr[0]) | ((unsigned int)f2bf(hr[1]) << 16);
            *(unsigned int*)(&Bu[iim[u]]) =
                (unsigned int)f2bf(hi[0]) | ((unsigned int)f2bf(hi[1]) << 16);
        }
    }
}

extern "C" void kernel_launch(void* const* d_in, const int* in_sizes, int n_in,
                              void* d_out, int out_size, void* d_ws, size_t ws_size,
                              hipStream_t stream) {
    const float* inputs    = (const float*)d_in[0];
    const float* h_re      = (const float*)d_in[1];
    const float* h_im      = (const float*)d_in[2];
    const float* nu_log    = (const float*)d_in[3];
    const float* theta_log = (const float*)d_in[4];
    const float* gamma_log = (const float*)d_in[5];
    const float* B_re      = (const float*)d_in[6];
    const float* B_im      = (const float*)d_in[7];
    const float* C_re      = (const float*)d_in[8];
    const float* C_im      = (const float*)d_in[9];
    const float* Dv        = (const float*)d_in[10];
    float* out = (float*)d_out;
    float* ws  = (float*)d_ws;
    ushort_t* wb = (ushort_t*)(ws + WS_WB_BF);
    ushort_t* wc = (ushort_t*)(ws + WS_WC_BF);
    ushort_t* bu = (ushort_t*)(ws + WS_BU);

    prep_w<<<1024, 256, 0, stream>>>(B_re, B_im, gamma_log, C_re, C_im, wb, wc);

    // GEMM1: Bu = X . Wb^T (fp32 X reg-staged; swapped MFMA; tiled Bu out)
    gemm_mfma<0><<<256, 512, 0, stream>>>(inputs, wb, (void*)bu, nullptr, inputs);

    scan_local<<<dim3(NCHUNK, 8), 256, 0, stream>>>(nu_log, theta_log, ws);
    scan_carry<<<B_DIM, 256, 0, stream>>>(nu_log, theta_log, ws, h_re, h_im,
                                          out, out_size);
    scan_apply<<<dim3(NCHUNK, 8), 256, 0, stream>>>(nu_log, theta_log, ws);

    // GEMM2: Y = H . Wc^T + D*x  (tiled H via gload_lds; fp32 out + fp32 X epi)
    gemm_mfma<1><<<256, 512, 0, stream>>>(bu, wc, (void*)out, Dv, inputs);
}

// Round 14
// 102.545 us; speedup vs baseline: 1.0116x; 1.0116x over previous
//
#include <hip/hip_runtime.h>
#include <hip/hip_bf16.h>
#include <math.h>

#define T_DIM 2048
#define B_DIM 16
#define M_DIM 512
#define H_DIM 256
#define KC 512
#define K_DIM 512
#define CHUNK 64
#define NCHUNK 32
#define NTILE 16            // K / 32 (pre-tiled granule count per 128-panel)

typedef unsigned short ushort_t;
typedef __attribute__((ext_vector_type(8))) short short8;
typedef __attribute__((ext_vector_type(8))) unsigned short ushort8;
typedef __attribute__((ext_vector_type(4))) float f32x4;

// ---- workspace layout (float offsets); total 17301504 floats = 69.2 MB ----
#define WS_CARRY 0            // 262144 floats (32*16*512)
#define WS_WB_BF 262144       // 262144 ushorts tiled
#define WS_WC_BF 393216       // 262144 ushorts tiled
#define WS_XB    524288       // 16777216 ushorts: X bf16 TILED
#define WS_BU    8912896      // 16777216 ushorts: Bu TILED, then H in place

// tiled index (ushorts): element (n,k) -> ((n/128)*16 + k/32)*4096 +
//   ((k/8)%4)*1024 + (n%128)*8 + k%8   — linear LDS staging order.
__device__ inline int tidx(int n, int k) {
    return (((n >> 7) * 16 + (k >> 5)) << 12) + (((k >> 3) & 3) << 10)
         + ((n & 127) << 3) + (k & 7);
}

__device__ inline ushort_t f2bf(float f) {
    __hip_bfloat16 h = __float2bfloat16(f);
    return *reinterpret_cast<ushort_t*>(&h);
}
__device__ inline float bf2f(ushort_t u) {
    union { unsigned int i; float f; } v;
    v.i = ((unsigned int)u) << 16;
    return v.f;
}

// Merged prep: blocks [0,8192) convert X fp32 -> bf16 TILED; blocks
// [8192,9216) build the bf16 pre-tiled weights.
__global__ __launch_bounds__(256) void prep_all(
        const float* __restrict__ X, ushort_t* __restrict__ Xb,
        const float* __restrict__ B_re, const float* __restrict__ B_im,
        const float* __restrict__ gamma_log,
        const float* __restrict__ C_re, const float* __restrict__ C_im,
        ushort_t* __restrict__ wb, ushort_t* __restrict__ wc) {
    int bid = blockIdx.x;
    if (bid < 8192) {
        int f = bid * 256 + threadIdx.x;          // 0..2097151
        int n = f >> 6, ko = f & 63;
        const float* p = X + (size_t)n * 512 + ko * 8;
        float4 a = *(const float4*)p;
        float4 b = *(const float4*)(p + 4);
        ushort8 u;
        u[0] = f2bf(a.x); u[1] = f2bf(a.y); u[2] = f2bf(a.z); u[3] = f2bf(a.w);
        u[4] = f2bf(b.x); u[5] = f2bf(b.y); u[6] = f2bf(b.z); u[7] = f2bf(b.w);
        *(ushort8*)(&Xb[(((n >> 7) * 16 + (ko >> 2)) << 12) + ((ko & 3) << 10)
                        + ((n & 127) << 3)]) = u;
    } else {
        int idx = (bid - 8192) * 256 + threadIdx.x;  // 0..262143
        int e    = idx & 7;
        int slot = (idx >> 3) & 511;
        int row  = slot & 127;
        int ks   = slot >> 7;
        int t    = (idx >> 12) & 15;
        int blk  = idx >> 16;
        int j = blk * 128 + row;
        int k = t * 32 + ks * 8 + e;
        float v;
        if (j < 256) v = expf(gamma_log[j])       * B_re[j * 512 + k];
        else         v = expf(gamma_log[j - 256]) * B_im[(j - 256) * 512 + k];
        wb[idx] = f2bf(v);
        float w;
        if (k < 256) w =  C_re[j * 256 + k];
        else         w = -C_im[j * 256 + (k - 256)];
        wc[idx] = f2bf(w);
    }
}

// NT GEMM via MFMA bf16, 256x256 tile, BK=64, 8 waves. R12-proven 2-phase
// loop (2 LDS dbufs for A, unroll-2 static indices, plain __syncthreads).
// NEW: the B operand (weights, 512KB, L2-resident on every XCD) is read
// DIRECTLY global->register — the pre-tiled layout makes each MFMA frag 16B
// contiguous (lanes l16 -> 256B contiguous). B-frag loads are issued BEFORE
// the A staging loads each step, so the compiler's FIFO vmcnt wait for bfr
// leaves the staging loads in flight. Halves barrier drain payload + LDS.
// MODE 0 (GEMM1): swapped operands mfma(W,X) -> packed uint2 tiled Bu out.
// MODE 1 (GEMM2): normal order, fp32 natural out + D[col]*Xb epilogue.
// Grid 1-D 256: id = g*16 + j*8 + x -> rb = g*8+x (0..127), nb = j (0..1);
// the 2 col-panels of a row-panel are spaced 8 ids -> same XCD.
template <int MODE>
__global__ __launch_bounds__(512) void gemm_mfma(
    const ushort_t* __restrict__ A, const ushort_t* __restrict__ W,
    void* __restrict__ Cv, const float* __restrict__ Dv,
    const ushort_t* __restrict__ Xb) {
    __shared__ ushort_t Asl[2][4][4096];   // [buf][q*2+kk][slot] : 64KB
    const int tid = threadIdx.x;           // 0..511
    const int id = blockIdx.x;
    const int rb = ((id >> 4) << 3) + (id & 7);   // row-panel-pair 0..127
    const int nb = (id >> 3) & 1;                 // col-panel-pair 0..1
    const int bm = rb << 8, bn = nb << 8;
    const int lane = tid & 63, wid = tid >> 6;    // 8 waves
    const int wr  = (wid >> 2) << 7;       // 0 / 128
    const int wcc = (wid & 3) << 6;        // 0,64,128,192
    const int l16 = lane & 15, ksl = lane >> 4;

    f32x4 acc[MODE == 0 ? 4 : 8][MODE == 0 ? 8 : 4] = {};

    // Direct-global W frag bases: col j = bn + wcc + n*16 + l16; granule
    // (t*2+kk) advances by 4096 ushorts.
    size_t wbase[4];
#pragma unroll
    for (int n = 0; n < 4; ++n) {
        int j = bn + wcc + n * 16 + l16;
        wbase[n] = (size_t)((j >> 7) * 16) * 4096 + (size_t)ksl * 1024
                 + (size_t)(j & 127) * 8;
    }

    auto stage = [&](int t, int buf) {     // A only: 4 gload_lds / thread
#pragma unroll
        for (int q = 0; q < 2; ++q)
#pragma unroll
            for (int kk = 0; kk < 2; ++kk) {
                size_t ab = ((size_t)((2 * rb + q) * NTILE + (2 * t + kk))) * 4096;
                __builtin_amdgcn_global_load_lds(
                    (const __attribute__((address_space(1))) void*)(A + ab + tid * 8),
                    (__attribute__((address_space(3))) void*)(&Asl[buf][q * 2 + kk][tid * 8]),
                    16, 0, 0);
            }
    };

    stage(0, 0);
    __syncthreads();

    int cur = 0;
#pragma unroll 2
    for (int t = 0; t < 8; ++t) {
        const int nxt = cur ^ 1;
        // B frags for this step FIRST (so their vmcnt wait excludes staging)
        short8 bfr2[2][4];
#pragma unroll
        for (int kk = 0; kk < 2; ++kk)
#pragma unroll
            for (int n = 0; n < 4; ++n)
                bfr2[kk][n] = *(const short8*)(&W[wbase[n] + (size_t)(t * 2 + kk) * 4096]);
        if (t + 1 < 8) stage(t + 1, nxt);
#pragma unroll
        for (int kk = 0; kk < 2; ++kk) {
            short8 afr[8];
#pragma unroll
            for (int m = 0; m < 8; ++m) {
                int row = wr + m * 16 + l16;       // 0..255
                afr[m] = *(const short8*)(&Asl[cur][(row >> 7) * 2 + kk]
                                              [ksl * 1024 + (row & 127) * 8]);
            }
            if constexpr (MODE == 0) {
#pragma unroll
                for (int i = 0; i < 4; ++i)       // i: W-frag (k axis)
#pragma unroll
                    for (int j = 0; j < 8; ++j)   // j: X-frag (n axis)
                        acc[i][j] = __builtin_amdgcn_mfma_f32_16x16x32_bf16(
                            bfr2[kk][i], afr[j], acc[i][j], 0, 0, 0);
            } else {
#pragma unroll
                for (int i = 0; i < 8; ++i)       // i: A-frag (H rows)
#pragma unroll
                    for (int j = 0; j < 4; ++j)   // j: W-frag (out cols)
                        acc[i][j] = __builtin_amdgcn_mfma_f32_16x16x32_bf16(
                            afr[i], bfr2[kk][j], acc[i][j], 0, 0, 0);
            }
        }
        __syncthreads();
        cur = nxt;
    }

    const int fr = (lane >> 4) << 2;
    if constexpr (MODE == 0) {
        // D row axis = W-col k (4 consecutive), D col axis (l16) = X-row n.
        ushort_t* Bu = (ushort_t*)Cv;
#pragma unroll
        for (int i = 0; i < 4; ++i) {
            int k0 = bn + wcc + i * 16 + fr;      // 4-aligned k quad
#pragma unroll
            for (int j = 0; j < 8; ++j) {
                int n = bm + wr + j * 16 + l16;
                uint2 p;
                p.x = (unsigned int)f2bf(acc[i][j][0])
                    | ((unsigned int)f2bf(acc[i][j][1]) << 16);
                p.y = (unsigned int)f2bf(acc[i][j][2])
                    | ((unsigned int)f2bf(acc[i][j][3]) << 16);
                size_t off = ((size_t)((n >> 7) * 16 + (k0 >> 5)) << 12)
                           + (((k0 >> 3) & 3) << 10) + ((n & 127) << 3) + (k0 & 7);
                *(uint2*)(&Bu[off]) = p;
            }
        }
    } else {
        // natural fp32 out: row = H-row, col via l16 (64B coalesced)
#pragma unroll
        for (int i = 0; i < 8; ++i) {
#pragma unroll
            for (int j = 0; j < 4; ++j) {
#pragma unroll
                for (int r = 0; r < 4; ++r) {
                    int row = bm + wr + i * 16 + fr + r;
                    int col = bn + wcc + j * 16 + l16;
                    size_t o = (size_t)row * 512 + col;
                    ((float*)Cv)[o] = acc[i][j][r] + Dv[col] * bf2f(Xb[tidx(row, col)]);
                }
            }
        }
    }
}

// Scan pass A: block = (chunk c, h-slab s); threads = 16 b x 16 h-pairs.
// Batch-8 loads (addresses independent of recurrence) to hide HBM latency.
__global__ __launch_bounds__(256) void scan_local(const float* __restrict__ nu_log,
        const float* __restrict__ theta_log, float* __restrict__ ws) {
    const int c = blockIdx.x;
    const int s = blockIdx.y;
    const int b = threadIdx.x >> 4;
    const int h0 = s * 32 + (threadIdx.x & 15) * 2;
    float lr[2], li[2];
#pragma unroll
    for (int q = 0; q < 2; ++q) {
        float nu = expf(nu_log[h0 + q]);
        float th = expf(theta_log[h0 + q]);
        float r  = expf(-nu);
        lr[q] = r * cosf(th); li[q] = r * sinf(th);
    }
    const ushort_t* Bu = (const ushort_t*)(ws + WS_BU);
    float hr[2] = {0.f, 0.f}, hi[2] = {0.f, 0.f};
    for (int l0 = 0; l0 < CHUNK; l0 += 8) {
        unsigned int vre[8], vim[8];
#pragma unroll
        for (int u = 0; u < 8; ++u) {
            int n = (c * CHUNK + l0 + u) * B_DIM + b;
            vre[u] = *(const unsigned int*)(&Bu[tidx(n, h0)]);
            vim[u] = *(const unsigned int*)(&Bu[tidx(n, h0 + 256)]);
        }
#pragma unroll
        for (int u = 0; u < 8; ++u) {
#pragma unroll
            for (int q = 0; q < 2; ++q) {
                float br = bf2f((ushort_t)(q ? (vre[u] >> 16) : (vre[u] & 0xffff)));
                float bi = bf2f((ushort_t)(q ? (vim[u] >> 16) : (vim[u] & 0xffff)));
                float nr = fmaf(lr[q], hr[q], fmaf(-li[q], hi[q], br));
                float ni = fmaf(lr[q], hi[q], fmaf(li[q], hr[q], bi));
                hr[q] = nr; hi[q] = ni;
            }
        }
    }
    size_t cb = (size_t)(c * B_DIM + b) * KC;
    *(float2*)(&ws[WS_CARRY + cb + h0])       = make_float2(hr[0], hr[1]);
    *(float2*)(&ws[WS_CARRY + cb + 256 + h0]) = make_float2(hi[0], hi[1]);
}

// Pass B: sequential over 32 chunk aggregates; h_final planar re/im to out tail.
__global__ __launch_bounds__(256) void scan_carry(const float* __restrict__ nu_log,
        const float* __restrict__ theta_log, float* __restrict__ ws,
        const float* __restrict__ h_re, const float* __restrict__ h_im,
        float* __restrict__ out, int out_size) {
    const int b = blockIdx.x;
    const int h = threadIdx.x;
    const float nu = expf(nu_log[h]);
    const float th = expf(theta_log[h]);
    const float rL  = expf(-64.f * nu);
    const float thL = 64.f * th;
    const float Lr = rL * cosf(thL), Li = rL * sinf(thL);
    float cr = h_re[b * H_DIM + h], ci = h_im[b * H_DIM + h];
    for (int c = 0; c < NCHUNK; ++c) {
        size_t cidx = ((size_t)(c * B_DIM + b)) * KC + h;
        float sr = ws[WS_CARRY + cidx], si = ws[WS_CARRY + cidx + 256];
        ws[WS_CARRY + cidx]       = cr;
        ws[WS_CARRY + cidx + 256] = ci;
        float nr = fmaf(Lr, cr, fmaf(-Li, ci, sr));
        float ni = fmaf(Lr, ci, fmaf(Li, cr, si));
        cr = nr; ci = ni;
    }
    const size_t base = (size_t)T_DIM * B_DIM * M_DIM;
    const size_t idx  = (size_t)b * H_DIM + h;
    size_t ore = base + idx;
    size_t oim = base + (size_t)B_DIM * H_DIM + idx;
    if (ore < (size_t)out_size) out[ore] = cr;
    if (oim < (size_t)out_size) out[oim] = ci;
}

// Pass C: replay chunk from carry-in; overwrite Bu IN PLACE (tiled) with h_t.
__global__ __launch_bounds__(256) void scan_apply(const float* __restrict__ nu_log,
        const float* __restrict__ theta_log, float* __restrict__ ws) {
    const int c = blockIdx.x;
    const int s = blockIdx.y;
    const int b = threadIdx.x >> 4;
    const int h0 = s * 32 + (threadIdx.x & 15) * 2;
    float lr[2], li[2];
#pragma unroll
    for (int q = 0; q < 2; ++q) {
        float nu = expf(nu_log[h0 + q]);
        float th = expf(theta_log[h0 + q]);
        float r  = expf(-nu);
        lr[q] = r * cosf(th); li[q] = r * sinf(th);
    }
    ushort_t* Bu = (ushort_t*)(ws + WS_BU);
    size_t cb = (size_t)(c * B_DIM + b) * KC;
    float2 f2r = *(const float2*)(&ws[WS_CARRY + cb + h0]);
    float2 f2i = *(const float2*)(&ws[WS_CARRY + cb + 256 + h0]);
    float hr[2] = {f2r.x, f2r.y}, hi[2] = {f2i.x, f2i.y};
    for (int l0 = 0; l0 < CHUNK; l0 += 8) {
        unsigned int vre[8], vim[8];
        int ire[8], iim[8];
#pragma unroll
        for (int u = 0; u < 8; ++u) {
            int n = (c * CHUNK + l0 + u) * B_DIM + b;
            ire[u] = tidx(n, h0);
            iim[u] = tidx(n, h0 + 256);
            vre[u] = *(const unsigned int*)(&Bu[ire[u]]);
            vim[u] = *(const unsigned int*)(&Bu[iim[u]]);
        }
#pragma unroll
        for (int u = 0; u < 8; ++u) {
#pragma unroll
            for (int q = 0; q < 2; ++q) {
                float br = bf2f((ushort_t)(q ? (vre[u] >> 16) : (vre[u] & 0xffff)));
                float bi = bf2f((ushort_t)(q ? (vim[u] >> 16) : (vim[u] & 0xffff)));
                float nr = fmaf(lr[q], hr[q], fmaf(-li[q], hi[q], br));
                float ni = fmaf(lr[q], hi[q], fmaf(li[q], hr[q], bi));
                hr[q] = nr; hi[q] = ni;
            }
            *(unsigned int*)(&Bu[ire[u]]) =
                (unsigned int)f2bf(hr[0]) | ((unsigned int)f2bf(hr[1]) << 16);
            *(unsigned int*)(&Bu[iim[u]]) =
                (unsigned int)f2bf(hi[0]) | ((unsigned int)f2bf(hi[1]) << 16);
        }
    }
}

extern "C" void kernel_launch(void* const* d_in, const int* in_sizes, int n_in,
                              void* d_out, int out_size, void* d_ws, size_t ws_size,
                              hipStream_t stream) {
    const float* inputs    = (const float*)d_in[0];
    const float* h_re      = (const float*)d_in[1];
    const float* h_im      = (const float*)d_in[2];
    const float* nu_log    = (const float*)d_in[3];
    const float* theta_log = (const float*)d_in[4];
    const float* gamma_log = (const float*)d_in[5];
    const float* B_re      = (const float*)d_in[6];
    const float* B_im      = (const float*)d_in[7];
    const float* C_re      = (const float*)d_in[8];
    const float* C_im      = (const float*)d_in[9];
    const float* Dv        = (const float*)d_in[10];
    float* out = (float*)d_out;
    float* ws  = (float*)d_ws;
    ushort_t* wb = (ushort_t*)(ws + WS_WB_BF);
    ushort_t* wc = (ushort_t*)(ws + WS_WC_BF);
    ushort_t* xb = (ushort_t*)(ws + WS_XB);
    ushort_t* bu = (ushort_t*)(ws + WS_BU);

    prep_all<<<9216, 256, 0, stream>>>(inputs, xb, B_re, B_im, gamma_log,
                                       C_re, C_im, wb, wc);

    // GEMM1: Bu = X . Wb^T (swapped MFMA; W direct-from-L2; tiled Bu out)
    gemm_mfma<0><<<256, 512, 0, stream>>>(xb, wb, (void*)bu, nullptr, nullptr);

    scan_local<<<dim3(NCHUNK, 8), 256, 0, stream>>>(nu_log, theta_log, ws);
    scan_carry<<<B_DIM, 256, 0, stream>>>(nu_log, theta_log, ws, h_re, h_im,
                                          out, out_size);
    scan_apply<<<dim3(NCHUNK, 8), 256, 0, stream>>>(nu_log, theta_log, ws);

    // GEMM2: Y = H . Wc^T + D*x  (W direct-from-L2; fp32 out + Xb epilogue)
    gemm_mfma<1><<<256, 512, 0, stream>>>(bu, wc, (void*)out, Dv, xb);
}